// Round 4
// baseline (1055.126 us; speedup 1.0000x reference)
//
#include <hip/hip_runtime.h>

#define TT 2048
#define BB 256
#define XX 64
#define HH 128
#define YY 32
#define SSTR 20          // padded h-slice stride (16 data + 4 pad floats)
#define HBUF (8 * SSTR)  // 160 floats per h buffer

// J=4, K=8 decomposition: 256 threads = 4 waves.
// Thread (wave w, lane l): kg = l>>3 (k-group: h[16kg..+15], x[8kg..+7]),
//                          jg = w*8 + (l&7), owns j = 4*jg .. 4*jg+3.
// Weights (96 floats) in registers; h in padded LDS (conflict-free b128
// broadcast); x direct from global, prefetched one step ahead (VMEM pipe,
// off the DS unit). k-reduce: DPP row_ror:8 (VALU) + shfl_xor 16/32.
// R2 lesson: DS-instruction throughput (~12 cyc/b128, per-CU serialized)
// was the wall at 96 b128/step; this design needs 16.
// R3 lesson: bias must be added AFTER the 8-way k-reduction (was 8x-counted).

static __device__ __forceinline__ void pin4(float4& v) {
    asm volatile("" : "+v"(v.x), "+v"(v.y), "+v"(v.z), "+v"(v.w));
}

static __device__ __forceinline__ float xor8_dpp(float v) {
    // row_ror:8 within 16-lane rows == xor-8 partner exchange (VALU, no DS)
    return __int_as_float(__builtin_amdgcn_update_dpp(
        0, __float_as_int(v), 0x128, 0xf, 0xf, true));
}

#define FMA4(a, wv, hv)                                          \
    do {                                                         \
        a = fmaf((wv).x, (hv).x, a); a = fmaf((wv).y, (hv).y, a);\
        a = fmaf((wv).z, (hv).z, a); a = fmaf((wv).w, (hv).w, a);\
    } while (0)

__global__ __launch_bounds__(256)
__attribute__((amdgpu_waves_per_eu(1, 1)))
void rnn_persist_kernel(const float* __restrict__ x,
                        const float* __restrict__ W_ih,
                        const float* __restrict__ W_hh,
                        const float* __restrict__ b_ih,
                        const float* __restrict__ b_hh,
                        const float* __restrict__ W_out,
                        const float* __restrict__ b_out,
                        float* __restrict__ out)
{
    __shared__ float h_lds[2][HBUF];

    const int tid  = threadIdx.x;
    const int b    = blockIdx.x;
    const int w    = tid >> 6;
    const int lane = tid & 63;
    const int kg   = lane >> 3;           // 0..7
    const int jg   = w * 8 + (lane & 7);  // 0..31
    const int j0   = jg * 4;

    // ---- weights into registers (96 floats), pinned ----
    float4 whh[16];  // 4 j x 4 chunks of 4 (h k-slice: 16 floats per j)
    float4 wih[8];   // 4 j x 2 chunks of 4 (x k-slice: 8 floats per j)
    float  bs[4];
    #pragma unroll
    for (int jj = 0; jj < 4; ++jj) {
        const float4* ph = (const float4*)(W_hh + (j0 + jj) * HH + kg * 16);
        whh[jj*4+0] = ph[0]; whh[jj*4+1] = ph[1];
        whh[jj*4+2] = ph[2]; whh[jj*4+3] = ph[3];
        const float4* pi = (const float4*)(W_ih + (j0 + jj) * XX + kg * 8);
        wih[jj*2+0] = pi[0]; wih[jj*2+1] = pi[1];
        bs[jj] = b_ih[j0 + jj] + b_hh[j0 + jj];
    }
    #pragma unroll
    for (int k = 0; k < 16; ++k) pin4(whh[k]);
    #pragma unroll
    for (int k = 0; k < 8; ++k)  pin4(wih[k]);

    const float* xg = x + (size_t)b * TT * XX + kg * 8;

    if (tid < HBUF) h_lds[0][tid] = 0.f;

    // x for step 0
    float4 xc0 = ((const float4*)xg)[0];
    float4 xc1 = ((const float4*)xg)[1];
    __syncthreads();

    const int woff = (jg >> 2) * SSTR + (j0 & 15);  // write slot for j0..j0+3

    int par = 0;
    for (int t = 0; t < TT; ++t) {
        // prefetch x for t+1 (independent of h -> latency fully hidden)
        const int tn = (t + 1 < TT) ? t + 1 : t;
        const float4* xgn = (const float4*)(xg + (size_t)tn * XX);
        float4 xn0 = xgn[0];
        float4 xn1 = xgn[1];

        float s0 = 0.f, s1 = 0.f, s2 = 0.f, s3 = 0.f;

        // x-projection partials (off critical path)
        FMA4(s0, wih[0], xc0); FMA4(s0, wih[1], xc1);
        FMA4(s1, wih[2], xc0); FMA4(s1, wih[3], xc1);
        FMA4(s2, wih[4], xc0); FMA4(s2, wih[5], xc1);
        FMA4(s3, wih[6], xc0); FMA4(s3, wih[7], xc1);

        // h slice (16 floats, broadcast within kg-group, conflict-free pad)
        const float* hp = &h_lds[par][kg * SSTR];
        const float4 h0 = ((const float4*)hp)[0];
        const float4 h1 = ((const float4*)hp)[1];
        const float4 h2 = ((const float4*)hp)[2];
        const float4 h3 = ((const float4*)hp)[3];

        FMA4(s0, whh[0],  h0); FMA4(s0, whh[1],  h1);
        FMA4(s0, whh[2],  h2); FMA4(s0, whh[3],  h3);
        FMA4(s1, whh[4],  h0); FMA4(s1, whh[5],  h1);
        FMA4(s1, whh[6],  h2); FMA4(s1, whh[7],  h3);
        FMA4(s2, whh[8],  h0); FMA4(s2, whh[9],  h1);
        FMA4(s2, whh[10], h2); FMA4(s2, whh[11], h3);
        FMA4(s3, whh[12], h0); FMA4(s3, whh[13], h1);
        FMA4(s3, whh[14], h2); FMA4(s3, whh[15], h3);

        // k-reduction across kg (lane bits 3,4,5), THEN bias, then tanh
        float hn0, hn1, hn2, hn3;
#define REDTANH(sv, bv, hv)                                          \
        do {                                                         \
            sv += xor8_dpp(sv);                                      \
            sv += __shfl_xor(sv, 16, 64);                            \
            sv += __shfl_xor(sv, 32, 64);                            \
            sv += bv;                                                \
            const float e_ = exp2f(sv * 2.885390082f);               \
            hv = fmaf(-2.f, __builtin_amdgcn_rcpf(e_ + 1.f), 1.f);   \
        } while (0)
        REDTANH(s0, bs[0], hn0);
        REDTANH(s1, bs[1], hn1);
        REDTANH(s2, bs[2], hn2);
        REDTANH(s3, bs[3], hn3);
#undef REDTANH

        if (lane < 8) {  // kg==0 lanes write the 4 finals as one b128
            *(float4*)&h_lds[par ^ 1][woff] = make_float4(hn0, hn1, hn2, hn3);
        }
        __syncthreads();
        par ^= 1;
        xc0 = xn0; xc1 = xn1;
    }

    // ---- readout: out[b, :] = h_last @ W_out^T + b_out ----
    if (tid < YY) {
        const float* h  = h_lds[par];
        const float* wr = W_out + tid * HH;
        float r0 = 0.f, r1 = 0.f, r2 = 0.f, r3 = 0.f;
        #pragma unroll
        for (int s8 = 0; s8 < 8; ++s8) {
            #pragma unroll
            for (int c = 0; c < 4; ++c) {
                const float4 wv = *(const float4*)(wr + s8 * 16 + c * 4);
                const float4 hv = *(const float4*)(h + s8 * SSTR + c * 4);
                r0 = fmaf(wv.x, hv.x, r0); r1 = fmaf(wv.y, hv.y, r1);
                r2 = fmaf(wv.z, hv.z, r2); r3 = fmaf(wv.w, hv.w, r3);
            }
        }
        out[b * YY + tid] = b_out[tid] + ((r0 + r1) + (r2 + r3));
    }
}

extern "C" void kernel_launch(void* const* d_in, const int* in_sizes, int n_in,
                              void* d_out, int out_size, void* d_ws, size_t ws_size,
                              hipStream_t stream) {
    const float* x     = (const float*)d_in[0];
    const float* W_ih  = (const float*)d_in[1];
    const float* W_hh  = (const float*)d_in[2];
    const float* b_ih  = (const float*)d_in[3];
    const float* b_hh  = (const float*)d_in[4];
    const float* W_out = (const float*)d_in[5];
    const float* b_out = (const float*)d_in[6];
    float* out = (float*)d_out;

    rnn_persist_kernel<<<BB, 256, 0, stream>>>(x, W_ih, W_hh, b_ih, b_hh,
                                               W_out, b_out, out);
}

// Round 6
// 838.576 us; speedup vs baseline: 1.2582x; 1.2582x over previous
//
#include <hip/hip_runtime.h>

#define TT 2048
#define BB 256
#define XX 64
#define HH 128
#define YY 32
#define SSTR 20          // padded h-slice stride (16 data + 4 pad floats)
#define HBUF (8 * SSTR)  // 160 floats per h buffer

// 512 threads = 8 waves = 2 waves/SIMD.  J=2 outputs/thread, Kg=8 k-groups.
// kg sits on lane bits {0,1,3}; jg on bits {2,4,5} (+wave).
// Reduction over kg = xor1 + xor2 (quad_perm, exact) + xor8 (row_ror:8,
// exact for ALL lanes regardless of ror direction: +/-8 mod 16 == ^8).
// R5 lesson: row_ror:n moves data toward HIGHER lanes (lane i <- i-n mod 16);
// only ror:8 is direction-agnostic -- never use ror:4 as "xor4".
// Weights (48 floats) pinned in registers; h in padded LDS (conflict-free
// b128 broadcast); x direct from global, prefetched one step ahead.
// R1: pin weights | R3: bias after reduction | R4: need 2 waves/SIMD + hw
// exp2/rcp (libm exp2f bloat + 1 wave/SIMD exposed all latency).

typedef float v2f __attribute__((ext_vector_type(2)));
typedef float v4f __attribute__((ext_vector_type(4)));

#define PKFMA(acc, a, b)                                              \
    asm("v_pk_fma_f32 %0, %1, %2, %0 op_sel:[0,0,0] op_sel_hi:[1,1,1]"\
        : "+v"(acc) : "v"(a), "v"(b))

template<int CTRL>
static __device__ __forceinline__ float dpp_add(float s) {
    const int t = __builtin_amdgcn_update_dpp(
        0, __float_as_int(s), CTRL, 0xF, 0xF, true);
    return s + __int_as_float(t);
}

static __device__ __forceinline__ void pin2(v2f& v) {
    asm volatile("" : "+v"(v));
}

#define LO2(v) __builtin_shufflevector(v, v, 0, 1)
#define HI2(v) __builtin_shufflevector(v, v, 2, 3)

__global__ __launch_bounds__(512, 2)
void rnn_persist_kernel(const float* __restrict__ x,
                        const float* __restrict__ W_ih,
                        const float* __restrict__ W_hh,
                        const float* __restrict__ b_ih,
                        const float* __restrict__ b_hh,
                        const float* __restrict__ W_out,
                        const float* __restrict__ b_out,
                        float* __restrict__ out)
{
    __shared__ __align__(16) float h_lds[2][HBUF];

    const int tid  = threadIdx.x;
    const int b    = blockIdx.x;
    const int w    = tid >> 6;                     // 0..7
    const int lane = tid & 63;
    const int kg   = (lane & 3) | ((lane >> 1) & 4);            // bits 0,1,3
    const int jgl  = ((lane >> 2) & 1) | (((lane >> 4) & 3) << 1); // bits 2,4,5
    const int jg   = w * 8 + jgl;                  // 0..63
    const int j0   = jg * 2;

    // ---- weights into registers (48 floats), pinned ----
    v2f whh2[2][8];
    v2f wih2[2][4];
    float bs[2];
    #pragma unroll
    for (int jj = 0; jj < 2; ++jj) {
        const v2f* ph = (const v2f*)(W_hh + (j0 + jj) * HH + kg * 16);
        #pragma unroll
        for (int c = 0; c < 8; ++c) whh2[jj][c] = ph[c];
        const v2f* pi = (const v2f*)(W_ih + (j0 + jj) * XX + kg * 8);
        #pragma unroll
        for (int c = 0; c < 4; ++c) wih2[jj][c] = pi[c];
        bs[jj] = b_ih[j0 + jj] + b_hh[j0 + jj];
    }
    #pragma unroll
    for (int jj = 0; jj < 2; ++jj) {
        #pragma unroll
        for (int c = 0; c < 8; ++c) pin2(whh2[jj][c]);
        #pragma unroll
        for (int c = 0; c < 4; ++c) pin2(wih2[jj][c]);
    }

    const float* xg = x + (size_t)b * TT * XX + kg * 8;
    v4f xc0 = ((const v4f*)xg)[0];
    v4f xc1 = ((const v4f*)xg)[1];

    if (tid < HBUF) h_lds[0][tid] = 0.f;
    __syncthreads();

    const int woff = (j0 >> 4) * SSTR + (j0 & 15);  // writer slot (kg==0)

    int par = 0;
    #pragma unroll 2
    for (int t = 0; t < TT; ++t) {
        // prefetch x for t+1 (VMEM pipe, hidden under compute)
        const int tn = (t < TT - 1) ? t + 1 : t;
        const v4f* xp = (const v4f*)(xg + (size_t)tn * XX);
        v4f xn0 = xp[0];
        v4f xn1 = xp[1];

        // h slice: 4 x b128 broadcast reads (8 kg-groups, pad -> conflict-free)
        const v4f* hp = (const v4f*)&h_lds[par][kg * SSTR];
        const v4f H0 = hp[0], H1 = hp[1], H2 = hp[2], H3 = hp[3];

        const v2f x2[4] = { LO2(xc0), HI2(xc0), LO2(xc1), HI2(xc1) };
        const v2f h2[8] = { LO2(H0), HI2(H0), LO2(H1), HI2(H1),
                            LO2(H2), HI2(H2), LO2(H3), HI2(H3) };

        float hn[2];
        #pragma unroll
        for (int jj = 0; jj < 2; ++jj) {
            v2f a = {0.f, 0.f}, c = {0.f, 0.f};
            PKFMA(a, wih2[jj][0], x2[0]); PKFMA(c, wih2[jj][1], x2[1]);
            PKFMA(a, wih2[jj][2], x2[2]); PKFMA(c, wih2[jj][3], x2[3]);
            PKFMA(a, whh2[jj][0], h2[0]); PKFMA(c, whh2[jj][1], h2[1]);
            PKFMA(a, whh2[jj][2], h2[2]); PKFMA(c, whh2[jj][3], h2[3]);
            PKFMA(a, whh2[jj][4], h2[4]); PKFMA(c, whh2[jj][5], h2[5]);
            PKFMA(a, whh2[jj][6], h2[6]); PKFMA(c, whh2[jj][7], h2[7]);
            float s = (a.x + a.y) + (c.x + c.y);
            // butterfly over kg bits: xor1, xor2 (quad_perm), xor8 (ror:8)
            s = dpp_add<0xB1>(s);    // quad_perm [1,0,3,2] = xor1
            s = dpp_add<0x4E>(s);    // quad_perm [2,3,0,1] = xor2
            s = dpp_add<0x128>(s);   // row_ror:8 = xor8 (direction-agnostic)
            s += bs[jj];             // bias AFTER reduction (R3)
            const float e = __builtin_amdgcn_exp2f(s * 2.885390082f);
            hn[jj] = fmaf(-2.f, __builtin_amdgcn_rcpf(e + 1.f), 1.f);
        }

        if (kg == 0) {
            v2f hw = { hn[0], hn[1] };
            *(v2f*)&h_lds[par ^ 1][woff] = hw;
        }
        __syncthreads();
        par ^= 1;
        xc0 = xn0; xc1 = xn1;
    }

    // ---- readout: out[b, :] = h_last @ W_out^T + b_out ----
    if (tid < YY) {
        const float* h  = h_lds[par];
        const float* wr = W_out + tid * HH;
        float r0 = 0.f, r1 = 0.f, r2 = 0.f, r3 = 0.f;
        #pragma unroll
        for (int s8 = 0; s8 < 8; ++s8) {
            #pragma unroll
            for (int c = 0; c < 4; ++c) {
                const float4 wv = *(const float4*)(wr + s8 * 16 + c * 4);
                const float4 hv = *(const float4*)(h + s8 * SSTR + c * 4);
                r0 = fmaf(wv.x, hv.x, r0); r1 = fmaf(wv.y, hv.y, r1);
                r2 = fmaf(wv.z, hv.z, r2); r3 = fmaf(wv.w, hv.w, r3);
            }
        }
        out[b * YY + tid] = b_out[tid] + ((r0 + r1) + (r2 + r3));
    }
}

extern "C" void kernel_launch(void* const* d_in, const int* in_sizes, int n_in,
                              void* d_out, int out_size, void* d_ws, size_t ws_size,
                              hipStream_t stream) {
    const float* x     = (const float*)d_in[0];
    const float* W_ih  = (const float*)d_in[1];
    const float* W_hh  = (const float*)d_in[2];
    const float* b_ih  = (const float*)d_in[3];
    const float* b_hh  = (const float*)d_in[4];
    const float* W_out = (const float*)d_in[5];
    const float* b_out = (const float*)d_in[6];
    float* out = (float*)d_out;

    rnn_persist_kernel<<<BB, 512, 0, stream>>>(x, W_ih, W_hh, b_ih, b_hh,
                                               W_out, b_out, out);
}